// Round 1
// baseline (307.682 us; speedup 1.0000x reference)
//
#include <hip/hip_runtime.h>

// Problem constants (B,C,T,H,HI) = (256, 64, 512, 8, 3)
constexpr int Tn = 512;
constexpr int Cn = 64;
constexpr int Bn = 256;

// Swap value with partner lane (lane^1) via DPP quad_perm [1,0,3,2] — pure VALU.
__device__ __forceinline__ float dpp_swap1(float v) {
    int i = __builtin_bit_cast(int, v);
    i = __builtin_amdgcn_mov_dpp(i, 0xB1 /*quad_perm 1,0,3,2*/, 0xF, 0xF, true);
    return __builtin_bit_cast(float, i);
}

// Bidirectional per-channel RNN scan.
// 2 lanes per (sequence, direction): lane pair (2i, 2i+1); each lane computes 4
// of the 8 hidden rows. Writes accF[seq*T + t] = U[c,0:8]·hf[t] and
// accB[seq*T + t] = U[c,8:16]·hb[t].
__global__ __launch_bounds__(256) void mrnn_scan(
    const float* __restrict__ x, const float* __restrict__ m, const float* __restrict__ d,
    const float* __restrict__ Wf, const float* __restrict__ Vf, const float* __restrict__ cf,
    const float* __restrict__ Wb, const float* __restrict__ Vb, const float* __restrict__ cbk,
    const float* __restrict__ U, float* __restrict__ accF, float* __restrict__ accB)
{
    const int g   = blockIdx.x * blockDim.x + threadIdx.x;
    const int ph  = g & 1;          // which half of the 8 hidden rows
    const int sd  = g >> 1;         // (dir, seq)
    const int dir = sd >> 14;       // 0 = forward, 1 = backward
    const int seq = sd & 16383;     // b*64 + c
    const int c   = seq & 63;
    const int base = seq * Tn;

    const float* W  = dir ? Wb  : Wf;
    const float* V  = dir ? Vb  : Vf;
    const float* cc = dir ? cbk : cf;

    // Per-lane weights. Wk[j][k] multiplies own h[k] (k<4) / partner p[k-4] (k>=4).
    float Wk[4][8], Vv[4][3], cbias[4], Uu[4];
    const int ob = 4 * ph;       // own row/col base
    const int pb = 4 - ob;       // partner col base
    #pragma unroll
    for (int j = 0; j < 4; ++j) {
        const int r = ob + j;
        #pragma unroll
        for (int k = 0; k < 4; ++k) {
            Wk[j][k]     = W[c*64 + r*8 + ob + k];
            Wk[j][4 + k] = W[c*64 + r*8 + pb + k];
        }
        #pragma unroll
        for (int k = 0; k < 3; ++k) Vv[j][k] = V[c*24 + r*3 + k];
        cbias[j] = cc[c*8 + r];
        Uu[j]    = U[c*16 + dir*8 + r];
    }

    float h[4] = {0.f, 0.f, 0.f, 0.f};
    float st[4];
    float* outp = (dir ? accB : accF) + base;

    // One recurrence step; returns pair-summed U·h_new.
    auto step = [&](float xv, float mv, float dv) -> float {
        float p[4];
        #pragma unroll
        for (int j = 0; j < 4; ++j) p[j] = dpp_swap1(h[j]);
        float a[4];
        #pragma unroll
        for (int j = 0; j < 4; ++j) {
            float s = cbias[j];
            s += Vv[j][0] * xv;
            s += Vv[j][1] * mv;
            s += Vv[j][2] * dv;
            #pragma unroll
            for (int k = 0; k < 4; ++k) s += Wk[j][k]     * h[k];
            #pragma unroll
            for (int k = 0; k < 4; ++k) s += Wk[j][4 + k] * p[k];
            a[j] = fmaxf(s, 0.f);
        }
        #pragma unroll
        for (int j = 0; j < 4; ++j) h[j] = a[j];
        float dot = Uu[0]*h[0] + Uu[1]*h[1] + Uu[2]*h[2] + Uu[3]*h[3];
        dot += dpp_swap1(dot);   // add partner's half
        return dot;
    };

    if (dir == 0) {
        // forward: step t uses input index max(t-1, 0); output slot = t
        st[0] = step(x[base], m[base], d[base]);               // t=0, u=0
        for (int j = 0; j < 128; ++j) {
            const float4 xq = *(const float4*)(x + base + 4*j);
            const float4 mq = *(const float4*)(m + base + 4*j);
            const float4 dq = *(const float4*)(d + base + 4*j);
            const float xa[4] = {xq.x, xq.y, xq.z, xq.w};
            const float ma[4] = {mq.x, mq.y, mq.z, mq.w};
            const float da[4] = {dq.x, dq.y, dq.z, dq.w};
            #pragma unroll
            for (int k = 0; k < 4; ++k) {
                const int t = 4*j + 1 + k;                     // uses u = 4j + k
                if (t < Tn) {
                    st[t & 3] = step(xa[k], ma[k], da[k]);
                    if (((t & 3) == 3) && ph == 0)
                        *(float4*)(outp + (t - 3)) = make_float4(st[0], st[1], st[2], st[3]);
                }
            }
        }
    } else {
        // backward: step s uses input index (s==0 ? T-1 : T-s); output slot = T-1-s
        st[3] = step(x[base + Tn-1], m[base + Tn-1], d[base + Tn-1]);  // s=0, pos=511
        for (int j = 0; j < 128; ++j) {
            const float4 xq = *(const float4*)(x + base + (508 - 4*j));
            const float4 mq = *(const float4*)(m + base + (508 - 4*j));
            const float4 dq = *(const float4*)(d + base + (508 - 4*j));
            const float xa[4] = {xq.x, xq.y, xq.z, xq.w};
            const float ma[4] = {mq.x, mq.y, mq.z, mq.w};
            const float da[4] = {dq.x, dq.y, dq.z, dq.w};
            #pragma unroll
            for (int k = 0; k < 4; ++k) {
                const int s = 4*j + 1 + k;                     // u = 511-4j-k -> element 3-k
                if (s < Tn) {
                    const int pos = 510 - 4*j - k;
                    st[pos & 3] = step(xa[3-k], ma[3-k], da[3-k]);
                    if (((pos & 3) == 0) && ph == 0)
                        *(float4*)(outp + pos) = make_float4(st[0], st[1], st[2], st[3]);
                }
            }
        }
    }
}

// Combine + cross-channel bottleneck MLP.
// x_est = relu(accF + accB + c0); h(3) = relu(V1·x_est + V2·m + Uz·x + U_b);
// out = W_w·h + W_b. One thread per (b, t); loops over the 64 channels.
__global__ __launch_bounds__(512) void mrnn_mix(
    const float* __restrict__ x, const float* __restrict__ m,
    const float* __restrict__ accF, const float* __restrict__ accB,
    const float* __restrict__ c0, const float* __restrict__ V1w,
    const float* __restrict__ V2w, const float* __restrict__ Uw,
    const float* __restrict__ Ub, const float* __restrict__ Ww,
    const float* __restrict__ Wbias, float* __restrict__ out)
{
    const int b = blockIdx.x;
    const int t = threadIdx.x;                 // 512 threads = all of T
    const int bbase = b * (Cn * Tn);

    float h0 = Ub[0], h1 = Ub[1], h2 = Ub[2];
    for (int c = 0; c < Cn; ++c) {
        const int off = bbase + c * Tn + t;
        const float xe = fmaxf(accF[off] + accB[off] + c0[c], 0.f);
        const float mv = m[off];
        const float xv = x[off];
        const float u0 = (c == 0) ? 0.f : Uw[0*Cn + c];
        const float u1 = (c == 1) ? 0.f : Uw[1*Cn + c];
        const float u2 = (c == 2) ? 0.f : Uw[2*Cn + c];
        h0 += V1w[0*Cn + c]*xe + V2w[0*Cn + c]*mv + u0*xv;
        h1 += V1w[1*Cn + c]*xe + V2w[1*Cn + c]*mv + u1*xv;
        h2 += V1w[2*Cn + c]*xe + V2w[2*Cn + c]*mv + u2*xv;
    }
    h0 = fmaxf(h0, 0.f); h1 = fmaxf(h1, 0.f); h2 = fmaxf(h2, 0.f);

    for (int c = 0; c < Cn; ++c) {
        out[bbase + c * Tn + t] =
            Wbias[c] + Ww[c*3 + 0]*h0 + Ww[c*3 + 1]*h1 + Ww[c*3 + 2]*h2;
    }
}

extern "C" void kernel_launch(void* const* d_in, const int* in_sizes, int n_in,
                              void* d_out, int out_size, void* d_ws, size_t ws_size,
                              hipStream_t stream)
{
    const float* x   = (const float*)d_in[0];
    const float* m   = (const float*)d_in[1];
    const float* d   = (const float*)d_in[2];
    const float* Wf  = (const float*)d_in[3];
    const float* Vf  = (const float*)d_in[4];
    const float* cf  = (const float*)d_in[5];
    const float* Wb  = (const float*)d_in[6];
    const float* Vb  = (const float*)d_in[7];
    const float* cb  = (const float*)d_in[8];
    const float* U   = (const float*)d_in[9];
    const float* c0  = (const float*)d_in[10];
    const float* V1w = (const float*)d_in[11];
    const float* V2w = (const float*)d_in[12];
    const float* Uw  = (const float*)d_in[13];
    const float* Ub  = (const float*)d_in[14];
    const float* Ww  = (const float*)d_in[15];
    const float* Wb_ = (const float*)d_in[16];
    float* out = (float*)d_out;

    // Workspace: accF and accB, each B*C*T floats (33.5 MB).
    float* accF = (float*)d_ws;
    float* accB = accF + (size_t)Bn * Cn * Tn;

    // 2 lanes * 16384 sequences * 2 directions = 65536 threads
    mrnn_scan<<<256, 256, 0, stream>>>(x, m, d, Wf, Vf, cf, Wb, Vb, cb, U, accF, accB);
    // one block per b, one thread per t
    mrnn_mix<<<Bn, Tn, 0, stream>>>(x, m, accF, accB, c0, V1w, V2w, Uw, Ub, Ww, Wb_, out);
}

// Round 2
// 154.781 us; speedup vs baseline: 1.9879x; 1.9879x over previous
//
#include <hip/hip_runtime.h>

// Problem constants (B,C,T,H,HI) = (256, 64, 512, 8, 3)
constexpr int Tn = 512;
constexpr int Cn = 64;
constexpr int Bn = 256;
constexpr int NS = 16384;   // number of sequences = B*C; acc planes are [t][seq]

// Swap value with partner lane (lane^1) via DPP quad_perm [1,0,3,2] — pure VALU.
__device__ __forceinline__ float dpp_swap1(float v) {
    int i = __builtin_bit_cast(int, v);
    i = __builtin_amdgcn_mov_dpp(i, 0xB1 /*quad_perm 1,0,3,2*/, 0xF, 0xF, true);
    return __builtin_bit_cast(float, i);
}

// Load one 64B line (16 floats) of x/m/d into register buffers.
#define LDLINE(XB, MB, DB, U0) do {                                         \
    const float4* _px = (const float4*)(xp + (U0));                         \
    const float4* _pm = (const float4*)(mp + (U0));                         \
    const float4* _pd = (const float4*)(dp + (U0));                         \
    _Pragma("unroll")                                                       \
    for (int q = 0; q < 4; ++q) {                                           \
        float4 v;                                                           \
        v = _px[q]; XB[4*q]=v.x; XB[4*q+1]=v.y; XB[4*q+2]=v.z; XB[4*q+3]=v.w; \
        v = _pm[q]; MB[4*q]=v.x; MB[4*q+1]=v.y; MB[4*q+2]=v.z; MB[4*q+3]=v.w; \
        v = _pd[q]; DB[4*q]=v.x; DB[4*q+1]=v.y; DB[4*q+2]=v.z; DB[4*q+3]=v.w; \
    }                                                                       \
} while (0)

// Run N forward steps using elements 0..N-1 of a line buffer; op advances +NS.
#define RUNF(XB, MB, DB, N) do {                                            \
    _Pragma("unroll")                                                       \
    for (int k = 0; k < (N); ++k) { *op = step(XB[k], MB[k], DB[k]); op += NS; } \
} while (0)

// Run N backward steps using elements 15..16-N of a line buffer; op advances -NS.
#define RUNB(XB, MB, DB, N) do {                                            \
    _Pragma("unroll")                                                       \
    for (int k = 0; k < (N); ++k) { *op = step(XB[15-k], MB[15-k], DB[15-k]); op -= NS; } \
} while (0)

// Bidirectional per-channel RNN scan.
// 2 lanes per (sequence, direction); lane pair exchanges half-states via DPP.
// Writes acc planes in t-major layout: acc[t*NS + seq] = U-half · h(t).
__global__ __launch_bounds__(256, 1) void mrnn_scan(
    const float* __restrict__ x, const float* __restrict__ m, const float* __restrict__ d,
    const float* __restrict__ Wf, const float* __restrict__ Vf, const float* __restrict__ cf,
    const float* __restrict__ Wb, const float* __restrict__ Vb, const float* __restrict__ cbk,
    const float* __restrict__ U, float* __restrict__ accF, float* __restrict__ accB)
{
    const int g   = blockIdx.x * blockDim.x + threadIdx.x;
    const int ph  = g & 1;          // which half of the 8 hidden rows
    const int sd  = g >> 1;         // (dir, seq)
    const int dir = sd >> 14;       // 0 = forward, 1 = backward
    const int seq = sd & 16383;     // b*64 + c
    const int c   = seq & 63;
    const long base = (long)seq * Tn;

    const float* W  = dir ? Wb  : Wf;
    const float* V  = dir ? Vb  : Vf;
    const float* cc = dir ? cbk : cf;

    // Per-lane weights. Wk[j][k] multiplies own h[k] (k<4) / partner p[k-4] (k>=4).
    float Wk[4][8], Vv[4][3], cbias[4], Uu[4];
    const int ob = 4 * ph;       // own row/col base
    const int pb = 4 - ob;       // partner col base
    #pragma unroll
    for (int j = 0; j < 4; ++j) {
        const int r = ob + j;
        #pragma unroll
        for (int k = 0; k < 4; ++k) {
            Wk[j][k]     = W[c*64 + r*8 + ob + k];
            Wk[j][4 + k] = W[c*64 + r*8 + pb + k];
        }
        #pragma unroll
        for (int k = 0; k < 3; ++k) Vv[j][k] = V[c*24 + r*3 + k];
        cbias[j] = cc[c*8 + r];
        Uu[j]    = U[c*16 + dir*8 + r];
    }

    float h[4] = {0.f, 0.f, 0.f, 0.f};
    const float* xp = x + base;
    const float* mp = m + base;
    const float* dp = d + base;
    float* op = (dir ? accB : accF) + seq;   // element stride NS per time step

    // One recurrence step; returns pair-summed U·h_new (both lanes get it).
    auto step = [&](float xv, float mv, float dv) -> float {
        float p0 = dpp_swap1(h[0]);
        float p1 = dpp_swap1(h[1]);
        float p2 = dpp_swap1(h[2]);
        float p3 = dpp_swap1(h[3]);
        float a[4];
        #pragma unroll
        for (int j = 0; j < 4; ++j) {
            float s = cbias[j];
            s += Vv[j][0] * xv;
            s += Vv[j][1] * mv;
            s += Vv[j][2] * dv;
            s += Wk[j][0] * h[0]; s += Wk[j][1] * h[1];
            s += Wk[j][2] * h[2]; s += Wk[j][3] * h[3];
            s += Wk[j][4] * p0;   s += Wk[j][5] * p1;
            s += Wk[j][6] * p2;   s += Wk[j][7] * p3;
            a[j] = fmaxf(s, 0.f);
        }
        h[0] = a[0]; h[1] = a[1]; h[2] = a[2]; h[3] = a[3];
        float dot = (Uu[0]*h[0] + Uu[1]*h[1]) + (Uu[2]*h[2] + Uu[3]*h[3]);
        dot += dpp_swap1(dot);   // add partner's half
        return dot;
    };

    float ax[16], am[16], ad[16], bx[16], bm[16], bd[16];

    if (dir == 0) {
        // forward: step t (0..511) uses u = max(t-1,0); line L covers u=16L..16L+15
        LDLINE(ax, am, ad, 0);     // L0
        LDLINE(bx, bm, bd, 16);    // L1
        *op = step(ax[0], am[0], ad[0]); op += NS;   // head t=0 (u=0)
        #pragma unroll 1
        for (int i = 0; i < 15; ++i) {
            RUNF(ax, am, ad, 16);                 // line 2i    (t = 32i+1 .. 32i+16)
            LDLINE(ax, am, ad, 32*i + 32);        // prefetch line 2i+2
            RUNF(bx, bm, bd, 16);                 // line 2i+1
            LDLINE(bx, bm, bd, 32*i + 48);        // prefetch line 2i+3
        }
        RUNF(ax, am, ad, 16);                     // line 30 (t=481..496)
        RUNF(bx, bm, bd, 15);                     // line 31 elems 0..14 (t=497..511)
    } else {
        // backward: step s uses u = (s==0 ? 511 : 512-s); writes pos = 511-s
        op += 511 * NS;
        LDLINE(ax, am, ad, 496);   // L31
        LDLINE(bx, bm, bd, 480);   // L30
        *op = step(ax[15], am[15], ad[15]); op -= NS;   // head s=0 (u=511, pos=511)
        #pragma unroll 1
        for (int i = 0; i < 15; ++i) {
            RUNB(ax, am, ad, 16);                 // line 31-2i (elem15 first)
            LDLINE(ax, am, ad, 16*(29 - 2*i));    // prefetch line 29-2i
            RUNB(bx, bm, bd, 16);                 // line 30-2i
            LDLINE(bx, bm, bd, 16*(28 - 2*i));    // prefetch line 28-2i
        }
        RUNB(ax, am, ad, 16);                     // line 1 (u=31..16, pos=30..15)
        RUNB(bx, bm, bd, 15);                     // line 0 elems 15..1 (u=15..1, pos=14..0)
    }
}

// Combine + cross-channel bottleneck MLP. One thread per (b,t).
// x_est = relu(accF + accB + c0); h(3) = relu(V1·x_est + V2·m + Uz·x + U_b);
// out = W_w·h + W_b.
__global__ __launch_bounds__(256, 2) void mrnn_mix(
    const float* __restrict__ x, const float* __restrict__ m,
    const float* __restrict__ accF, const float* __restrict__ accB,
    const float* __restrict__ c0, const float* __restrict__ V1w,
    const float* __restrict__ V2w, const float* __restrict__ Uw,
    const float* __restrict__ Ub, const float* __restrict__ Ww,
    const float* __restrict__ Wbias, float* __restrict__ out)
{
    const int bt = blockIdx.x * 256 + threadIdx.x;   // 0..131071
    const int b = bt >> 9;
    const int t = bt & 511;

    const float* aF = accF + (size_t)t * NS + b * Cn;   // 64 contiguous floats
    const float* aB = accB + (size_t)t * NS + b * Cn;
    const size_t xb = (size_t)b * (Cn * Tn) + t;

    float h0 = Ub[0], h1 = Ub[1], h2 = Ub[2];
    #pragma unroll 16
    for (int c = 0; c < Cn; ++c) {
        const float xe = fmaxf(aF[c] + aB[c] + c0[c], 0.f);
        const float mv = m[xb + (size_t)c * Tn];
        const float xv = x[xb + (size_t)c * Tn];
        const float u0 = (c == 0) ? 0.f : Uw[0*Cn + c];
        const float u1 = (c == 1) ? 0.f : Uw[1*Cn + c];
        const float u2 = (c == 2) ? 0.f : Uw[2*Cn + c];
        h0 += V1w[0*Cn + c]*xe + V2w[0*Cn + c]*mv + u0*xv;
        h1 += V1w[1*Cn + c]*xe + V2w[1*Cn + c]*mv + u1*xv;
        h2 += V1w[2*Cn + c]*xe + V2w[2*Cn + c]*mv + u2*xv;
    }
    h0 = fmaxf(h0, 0.f); h1 = fmaxf(h1, 0.f); h2 = fmaxf(h2, 0.f);

    float* opt = out + (size_t)b * (Cn * Tn) + t;
    #pragma unroll
    for (int c = 0; c < Cn; ++c) {
        opt[(size_t)c * Tn] = Wbias[c] + Ww[c*3 + 0]*h0 + Ww[c*3 + 1]*h1 + Ww[c*3 + 2]*h2;
    }
}

extern "C" void kernel_launch(void* const* d_in, const int* in_sizes, int n_in,
                              void* d_out, int out_size, void* d_ws, size_t ws_size,
                              hipStream_t stream)
{
    const float* x   = (const float*)d_in[0];
    const float* m   = (const float*)d_in[1];
    const float* d   = (const float*)d_in[2];
    const float* Wf  = (const float*)d_in[3];
    const float* Vf  = (const float*)d_in[4];
    const float* cf  = (const float*)d_in[5];
    const float* Wb  = (const float*)d_in[6];
    const float* Vb  = (const float*)d_in[7];
    const float* cb  = (const float*)d_in[8];
    const float* U   = (const float*)d_in[9];
    const float* c0  = (const float*)d_in[10];
    const float* V1w = (const float*)d_in[11];
    const float* V2w = (const float*)d_in[12];
    const float* Uw  = (const float*)d_in[13];
    const float* Ub  = (const float*)d_in[14];
    const float* Ww  = (const float*)d_in[15];
    const float* Wb_ = (const float*)d_in[16];
    float* out = (float*)d_out;

    // Workspace: accF and accB planes, each T*NS floats (33.5 MB), t-major.
    float* accF = (float*)d_ws;
    float* accB = accF + (size_t)Tn * NS;

    // 2 lanes * 16384 sequences * 2 directions = 65536 threads
    mrnn_scan<<<256, 256, 0, stream>>>(x, m, d, Wf, Vf, cf, Wb, Vb, cb, U, accF, accB);
    // one thread per (b,t) = 131072 threads
    mrnn_mix<<<512, 256, 0, stream>>>(x, m, accF, accB, c0, V1w, V2w, Uw, Ub, Ww, Wb_, out);
}

// Round 3
// 114.159 us; speedup vs baseline: 2.6952x; 1.3558x over previous
//
#include <hip/hip_runtime.h>

// Problem constants (B,C,T,H,HI) = (256, 64, 512, 8, 3)
constexpr int Tn = 512;
constexpr int Cn = 64;
constexpr int Bn = 256;
constexpr int NS = 16384;   // number of sequences = B*C; acc planes are [t][seq]

typedef float f2 __attribute__((ext_vector_type(2)));

// DPP move with compile-time control (quad_perm patterns).
template<int CTRL>
__device__ __forceinline__ float dppf(float v) {
    int i = __builtin_bit_cast(int, v);
    i = __builtin_amdgcn_mov_dpp(i, CTRL, 0xF, 0xF, true);
    return __builtin_bit_cast(float, i);
}

// Load one 64B line (16 floats) of x/m/d into scalar register buffers.
#define LDLINE(XB, MB, DB, U0) do {                                         \
    const float4* _px = (const float4*)(xp + (U0));                         \
    const float4* _pm = (const float4*)(mp + (U0));                         \
    const float4* _pd = (const float4*)(dp + (U0));                         \
    _Pragma("unroll")                                                       \
    for (int q = 0; q < 4; ++q) {                                           \
        float4 v;                                                           \
        v = _px[q]; XB[4*q]=v.x; XB[4*q+1]=v.y; XB[4*q+2]=v.z; XB[4*q+3]=v.w; \
        v = _pm[q]; MB[4*q]=v.x; MB[4*q+1]=v.y; MB[4*q+2]=v.z; MB[4*q+3]=v.w; \
        v = _pd[q]; DB[4*q]=v.x; DB[4*q+1]=v.y; DB[4*q+2]=v.z; DB[4*q+3]=v.w; \
    }                                                                       \
} while (0)

// Run N forward steps using elements 0..N-1 of a line buffer; op advances +NS.
#define RUNF(XB, MB, DB, N) do {                                            \
    _Pragma("unroll")                                                       \
    for (int k = 0; k < (N); ++k) { *op = step(XB[k], MB[k], DB[k]); op += NS; } \
} while (0)

// Run N backward steps using elements 15..16-N of a line buffer; op advances -NS.
#define RUNB(XB, MB, DB, N) do {                                            \
    _Pragma("unroll")                                                       \
    for (int k = 0; k < (N); ++k) { *op = step(XB[15-k], MB[15-k], DB[15-k]); op -= NS; } \
} while (0)

// Bidirectional per-channel RNN scan, quad decomposition:
// 4 lanes per (sequence, direction); lane q owns hidden rows {2q, 2q+1} as one
// float2. Full 8-state rebroadcast via quad_perm DPP each step. Row-pair math
// in packed fp32 (v_pk_fma_f32). Writes acc[t*NS + seq] = U-half · h(t).
__global__ __launch_bounds__(256, 2) void mrnn_scan(
    const float* __restrict__ x, const float* __restrict__ m, const float* __restrict__ d,
    const float* __restrict__ Wf, const float* __restrict__ Vf, const float* __restrict__ cf,
    const float* __restrict__ Wb, const float* __restrict__ Vb, const float* __restrict__ cbk,
    const float* __restrict__ U, float* __restrict__ accF, float* __restrict__ accB)
{
    const int g   = blockIdx.x * blockDim.x + threadIdx.x;
    const int q   = g & 3;          // lane-in-quad: owns rows 2q, 2q+1
    const int sd  = g >> 2;         // (dir, seq)
    const int dir = sd >> 14;       // 0 = forward, 1 = backward
    const int seq = sd & 16383;     // b*64 + c
    const int c   = seq & 63;
    const long base = (long)seq * Tn;

    const float* W  = dir ? Wb  : Wf;
    const float* V  = dir ? Vb  : Vf;
    const float* cc = dir ? cbk : cf;

    const int r0 = 2 * q;
    const int r1 = 2 * q + 1;

    // Packed per-lane weights: Wp[k] = (W[r0][k], W[r1][k]), etc.
    f2 Wp[8], Vp[3], cbp, Up;
    #pragma unroll
    for (int k = 0; k < 8; ++k) {
        Wp[k].x = W[c*64 + r0*8 + k];
        Wp[k].y = W[c*64 + r1*8 + k];
    }
    #pragma unroll
    for (int k = 0; k < 3; ++k) {
        Vp[k].x = V[c*24 + r0*3 + k];
        Vp[k].y = V[c*24 + r1*3 + k];
    }
    cbp.x = cc[c*8 + r0];  cbp.y = cc[c*8 + r1];
    Up.x  = U[c*16 + dir*8 + r0];
    Up.y  = U[c*16 + dir*8 + r1];

    f2 h = {0.f, 0.f};
    const float* xp = x + base;
    const float* mp = m + base;
    const float* dp = d + base;
    float* op = (dir ? accB : accF) + seq;   // element stride NS per time step

    // One recurrence step; returns quad-summed U·h_new (all 4 lanes get it).
    auto step = [&](float xv, float mv, float dv) -> float {
        // Rebuild full 8-state: h_{2o}=lane o's h.x, h_{2o+1}=lane o's h.y
        const float h0 = dppf<0x00>(h.x), h1 = dppf<0x00>(h.y);
        const float h2 = dppf<0x55>(h.x), h3 = dppf<0x55>(h.y);
        const float h4 = dppf<0xAA>(h.x), h5 = dppf<0xAA>(h.y);
        const float h6 = dppf<0xFF>(h.x), h7 = dppf<0xFF>(h.y);
        f2 acc = cbp;
        acc += Vp[0] * xv;
        acc += Vp[1] * mv;
        acc += Vp[2] * dv;
        acc += Wp[0] * h0;  acc += Wp[1] * h1;
        acc += Wp[2] * h2;  acc += Wp[3] * h3;
        acc += Wp[4] * h4;  acc += Wp[5] * h5;
        acc += Wp[6] * h6;  acc += Wp[7] * h7;
        acc.x = fmaxf(acc.x, 0.f);
        acc.y = fmaxf(acc.y, 0.f);
        h = acc;
        f2 dp2 = Up * acc;
        float pd = dp2.x + dp2.y;
        pd += dppf<0xB1>(pd);   // + lane^1
        pd += dppf<0x4E>(pd);   // + lane^2  -> full 8-row dot in all lanes
        return pd;
    };

    float ax[16], am[16], ad[16], bx[16], bm[16], bd[16];

    if (dir == 0) {
        // forward: step t (0..511) uses u = max(t-1,0); line L covers u=16L..16L+15
        LDLINE(ax, am, ad, 0);     // L0
        LDLINE(bx, bm, bd, 16);    // L1
        *op = step(ax[0], am[0], ad[0]); op += NS;   // head t=0 (u=0)
        #pragma unroll 1
        for (int i = 0; i < 15; ++i) {
            RUNF(ax, am, ad, 16);                 // line 2i    (t = 32i+1 .. 32i+16)
            LDLINE(ax, am, ad, 32*i + 32);        // prefetch line 2i+2
            RUNF(bx, bm, bd, 16);                 // line 2i+1
            LDLINE(bx, bm, bd, 32*i + 48);        // prefetch line 2i+3
        }
        RUNF(ax, am, ad, 16);                     // line 30 (t=481..496)
        RUNF(bx, bm, bd, 15);                     // line 31 elems 0..14 (t=497..511)
    } else {
        // backward: step s uses u = (s==0 ? 511 : 512-s); writes pos = 511-s
        op += 511 * NS;
        LDLINE(ax, am, ad, 496);   // L31
        LDLINE(bx, bm, bd, 480);   // L30
        *op = step(ax[15], am[15], ad[15]); op -= NS;   // head s=0 (u=511, pos=511)
        #pragma unroll 1
        for (int i = 0; i < 15; ++i) {
            RUNB(ax, am, ad, 16);                 // line 31-2i (elem15 first)
            LDLINE(ax, am, ad, 16*(29 - 2*i));    // prefetch line 29-2i
            RUNB(bx, bm, bd, 16);                 // line 30-2i
            LDLINE(bx, bm, bd, 16*(28 - 2*i));    // prefetch line 28-2i
        }
        RUNB(ax, am, ad, 16);                     // line 1 (u=31..16, pos=30..15)
        RUNB(bx, bm, bd, 15);                     // line 0 elems 15..1 (u=15..1, pos=14..0)
    }
}

// Combine + cross-channel bottleneck MLP. One thread per (b,t).
// x_est = relu(accF + accB + c0); h(3) = relu(V1·x_est + V2·m + Uz·x + U_b);
// out = W_w·h + W_b.
__global__ __launch_bounds__(256, 2) void mrnn_mix(
    const float* __restrict__ x, const float* __restrict__ m,
    const float* __restrict__ accF, const float* __restrict__ accB,
    const float* __restrict__ c0, const float* __restrict__ V1w,
    const float* __restrict__ V2w, const float* __restrict__ Uw,
    const float* __restrict__ Ub, const float* __restrict__ Ww,
    const float* __restrict__ Wbias, float* __restrict__ out)
{
    const int bt = blockIdx.x * 256 + threadIdx.x;   // 0..131071
    const int b = bt >> 9;
    const int t = bt & 511;

    const float4* aF4 = (const float4*)(accF + (size_t)t * NS + b * Cn);
    const float4* aB4 = (const float4*)(accB + (size_t)t * NS + b * Cn);
    const size_t xb = (size_t)b * (Cn * Tn) + t;

    float h0 = Ub[0], h1 = Ub[1], h2 = Ub[2];
    #pragma unroll
    for (int c4 = 0; c4 < 16; ++c4) {
        const float4 fa = aF4[c4];
        const float4 fb = aB4[c4];
        const float fav[4] = {fa.x, fa.y, fa.z, fa.w};
        const float fbv[4] = {fb.x, fb.y, fb.z, fb.w};
        #pragma unroll
        for (int j = 0; j < 4; ++j) {
            const int cch = 4*c4 + j;
            const float xe = fmaxf(fav[j] + fbv[j] + c0[cch], 0.f);
            const float mv = m[xb + (size_t)cch * Tn];
            const float xv = x[xb + (size_t)cch * Tn];
            const float u0 = (cch == 0) ? 0.f : Uw[0*Cn + cch];
            const float u1 = (cch == 1) ? 0.f : Uw[1*Cn + cch];
            const float u2 = (cch == 2) ? 0.f : Uw[2*Cn + cch];
            h0 += V1w[0*Cn + cch]*xe + V2w[0*Cn + cch]*mv + u0*xv;
            h1 += V1w[1*Cn + cch]*xe + V2w[1*Cn + cch]*mv + u1*xv;
            h2 += V1w[2*Cn + cch]*xe + V2w[2*Cn + cch]*mv + u2*xv;
        }
    }
    h0 = fmaxf(h0, 0.f); h1 = fmaxf(h1, 0.f); h2 = fmaxf(h2, 0.f);

    float* opt = out + (size_t)b * (Cn * Tn) + t;
    #pragma unroll
    for (int cch = 0; cch < Cn; ++cch) {
        opt[(size_t)cch * Tn] = Wbias[cch] + Ww[cch*3 + 0]*h0 + Ww[cch*3 + 1]*h1 + Ww[cch*3 + 2]*h2;
    }
}

extern "C" void kernel_launch(void* const* d_in, const int* in_sizes, int n_in,
                              void* d_out, int out_size, void* d_ws, size_t ws_size,
                              hipStream_t stream)
{
    const float* x   = (const float*)d_in[0];
    const float* m   = (const float*)d_in[1];
    const float* d   = (const float*)d_in[2];
    const float* Wf  = (const float*)d_in[3];
    const float* Vf  = (const float*)d_in[4];
    const float* cf  = (const float*)d_in[5];
    const float* Wb  = (const float*)d_in[6];
    const float* Vb  = (const float*)d_in[7];
    const float* cb  = (const float*)d_in[8];
    const float* U   = (const float*)d_in[9];
    const float* c0  = (const float*)d_in[10];
    const float* V1w = (const float*)d_in[11];
    const float* V2w = (const float*)d_in[12];
    const float* Uw  = (const float*)d_in[13];
    const float* Ub  = (const float*)d_in[14];
    const float* Ww  = (const float*)d_in[15];
    const float* Wb_ = (const float*)d_in[16];
    float* out = (float*)d_out;

    // Workspace: accF and accB planes, each T*NS floats (33.5 MB), t-major.
    float* accF = (float*)d_ws;
    float* accB = accF + (size_t)Tn * NS;

    // 4 lanes * 16384 sequences * 2 directions = 131072 threads
    mrnn_scan<<<512, 256, 0, stream>>>(x, m, d, Wf, Vf, cf, Wb, Vb, cb, U, accF, accB);
    // one thread per (b,t) = 131072 threads
    mrnn_mix<<<512, 256, 0, stream>>>(x, m, accF, accB, c0, V1w, V2w, Uw, Ub, Ww, Wb_, out);
}